// Round 7
// baseline (350.076 us; speedup 1.0000x reference)
//
#include <hip/hip_runtime.h>

// Problem constants: B=1, S=4096, D=768, H=12, Dh=64
#define S_LEN 4096
#define D_MODEL 768
#define N_HEADS 12
#define D_HEAD 64

typedef short bf16x8 __attribute__((ext_vector_type(8)));   // MFMA A/B operand (8 bf16, 4 VGPRs)
typedef float f32x4 __attribute__((ext_vector_type(4)));    // MFMA C/D operand (16x16)
typedef float f32x16 __attribute__((ext_vector_type(16)));  // MFMA C/D operand (32x32)
typedef float f32x4v __attribute__((ext_vector_type(4)));
typedef unsigned short u16;
typedef unsigned short u16x8 __attribute__((ext_vector_type(8)));
typedef unsigned int u32;

// fp32 -> bf16 round-to-nearest-even
__device__ __forceinline__ u16 f2bf(float f) {
  unsigned u = __float_as_uint(f);
  u += 0x7FFFu + ((u >> 16) & 1u);
  return (u16)(u >> 16);
}

// pack two fp32 -> 2x bf16 in one u32 (round-half-up)
__device__ __forceinline__ u32 pk2bf(float lo, float hi) {
  u32 a = __float_as_uint(hi) + 0x8000u;
  u32 b = __float_as_uint(lo) + 0x8000u;
  return __builtin_amdgcn_perm(a, b, 0x07060302u);
}

// async global->LDS, 16B per lane; LDS dest is wave-uniform base + lane*16 (m104 caveat)
__device__ __forceinline__ void gl_lds16(const void* g, void* l) {
  __builtin_amdgcn_global_load_lds(
      (const __attribute__((address_space(1))) void*)g,
      (__attribute__((address_space(3))) void*)l, 16, 0, 0);
}

// ---------------------------------------------------------------- conversion (single fused launch)
struct CvtArgs7 {
  const float* s[7];
  u16* d[7];
  long n[7];
};

__global__ __launch_bounds__(256) void cvt8_kernel(CvtArgs7 a) {
  const int z = blockIdx.z;
  const float* s = a.s[z];
  u16* d = a.d[z];
  long i = ((long)blockIdx.x * 256 + threadIdx.x) * 8;
  if (i >= a.n[z]) return;
  f32x4v v0 = *(const f32x4v*)(s + i);
  f32x4v v1 = *(const f32x4v*)(s + i + 4);
  u16x8 o;
#pragma unroll
  for (int j = 0; j < 4; ++j) { o[j] = f2bf(v0[j]); o[j + 4] = f2bf(v1[j]); }
  *(u16x8*)(d + i) = o;
}

// ---------------------------------------------------------------- projection GEMM
// Out[m][n] = (sum_k A[m][k] * W[n][k] + bias[n]) * scale
// TM = M-tile (128 or 64); N-tile fixed 128.
// mode 0: bf16 row-major (ld 768)
// mode 2: fp32 row-major
// mode 3: packed-K frag order: Kpk[((h*128+st)*4+s)*512 + (g*32+l31)*8 + j]
//         = K[seq=st*32+l31][d=s*16+g*8+j]  (flash S^T A-operand sequence)
// mode 4: packed-V frag order: Vpk[((h*128+st)*4+db*2+u)*512 + (g*32+l31)*8 + j]
//         = V[key=st*32+16u+(j&3)+8*(j>>2)+4g][d=db*32+l31]  (flash PV A-operand,
//         kappa swap-bits-2/3 baked in to match P's B-frag key order)
// Modes 3/4 (TM=128 only) bounce through 32KB LDS so global stores are
// coalesced dwordx4 (round-6 lesson: scattered u16 stores are the proj cost).
struct ProjArgs {
  const u16* A[3];
  const u16* W[3];
  const float* bias[3];
  void* out[3];
  float scale[3];
  int mode[3];
};

template <int TM>
__global__ __launch_bounds__(256, 2) void proj_kernel(ProjArgs args) {
  constexpr int MF = TM / 32;       // m-frags per wave
  constexpr int CA = TM / 16;       // A staging chunks (1KB each)
  const int z = blockIdx.z;
  const u16* __restrict__ A = args.A[z];
  const u16* __restrict__ W = args.W[z];
  const float* __restrict__ bias = args.bias[z];
  const float scale = args.scale[z];
  const int mode = args.mode[z];

  __shared__ u16 Al[TM * 32];
  __shared__ u16 Bl[128 * 32];
  __shared__ u16 Ep[TM == 128 ? 16384 : 1];  // packed-epilogue bounce (32KB)

  const int tid = threadIdx.x;
  const int w = tid >> 6, l = tid & 63;
  const int l15 = l & 15, quad = l >> 4;
  const int m0 = blockIdx.x * TM;
  const int n0 = blockIdx.y * 128;
  const int wm = (w & 1) * (TM / 2), wn = (w >> 1) * 64;
  const int crow = l >> 2, ccol = (l & 3) * 8;

  f32x4 acc[MF][4] = {};

  for (int kt = 0; kt < 24; ++kt) {
    const int k0 = kt * 32;
#pragma unroll
    for (int i = 0; i < CA / 4; ++i) {
      const int sub = w * (CA / 4) + i;
      const int row = sub * 16 + crow;
      gl_lds16(&A[(size_t)(m0 + row) * D_MODEL + k0 + ccol], &Al[sub * 512 + l * 8]);
    }
#pragma unroll
    for (int i = 0; i < 2; ++i) {
      const int sub = w * 2 + i;
      const int row = sub * 16 + crow;
      gl_lds16(&W[(size_t)(n0 + row) * D_MODEL + k0 + ccol], &Bl[sub * 512 + l * 8]);
    }
    __syncthreads();
    bf16x8 af[MF], bfr[4];
#pragma unroll
    for (int mf = 0; mf < MF; ++mf)
      af[mf] = *(const bf16x8*)&Al[(wm + mf * 16 + l15) * 32 + quad * 8];
#pragma unroll
    for (int nf = 0; nf < 4; ++nf)
      bfr[nf] = *(const bf16x8*)&Bl[(wn + nf * 16 + l15) * 32 + quad * 8];
#pragma unroll
    for (int mf = 0; mf < MF; ++mf)
#pragma unroll
      for (int nf = 0; nf < 4; ++nf)
        acc[mf][nf] = __builtin_amdgcn_mfma_f32_16x16x32_bf16(af[mf], bfr[nf], acc[mf][nf], 0, 0, 0);
    __syncthreads();
  }

  // C/D layout: col = lane&15, row = quad*4 + reg (m89/m91 verified)
  if (mode == 3 || mode == 4) {
    // write packed layout into Ep, then coalesced copy-out
#pragma unroll
    for (int nf = 0; nf < 4; ++nf) {
      const float bv = bias[n0 + wn + nf * 16 + l15];
#pragma unroll
      for (int mf = 0; mf < MF; ++mf) {
#pragma unroll
        for (int r = 0; r < 4; ++r) {
          const float v = acc[mf][nf][r] + bv;
          int off;
          if (mode == 3) {
            // chunk = hloc*16 + sloc*4 + s ; hloc=w>>1, sloc=(w&1)*2+(mf>>1), s=nf
            // intra = ((l15>>3)*32 + (mf&1)*16 + quad*4 + r)*8 + (l15&7)
            off = (((w >> 1) * 16 + ((w & 1) * 2 + (mf >> 1)) * 4 + nf) << 9) +
                  (((l15 >> 3) * 32 + (mf & 1) * 16 + quad * 4 + r) << 3) + (l15 & 7);
          } else {
            // chunk = hloc*16 + sloc*4 + db*2 + u ; db=nf>>1, u=mf&1
            // intra = ((quad&1)*32 + (nf&1)*16 + l15)*8 + r + 4*(quad>>1)
            off = (((w >> 1) * 16 + ((w & 1) * 2 + (mf >> 1)) * 4 + (nf >> 1) * 2 + (mf & 1)) << 9) +
                  (((quad & 1) * 32 + (nf & 1) * 16 + l15) << 3) + r + 4 * (quad >> 1);
          }
          Ep[off] = f2bf(v);
        }
      }
    }
    __syncthreads();
    // copy-out: per hloc, 16 contiguous 1KB chunks at ((hh0+hloc)*128+st0)*4
    const int hh0 = n0 >> 6, st0 = m0 >> 5;
    u16* outp = (u16*)args.out[z];
#pragma unroll
    for (int hloc = 0; hloc < 2; ++hloc) {
      u16* dst = outp + ((size_t)((hh0 + hloc) * 128 + st0) * 4) * 512;
#pragma unroll
      for (int c = 0; c < 4; ++c) {
        u16x8 v = *(u16x8*)&Ep[hloc * 8192 + w * 2048 + c * 512 + l * 8];
        *(u16x8*)(dst + w * 2048 + c * 512 + l * 8) = v;
      }
    }
  } else {
#pragma unroll
    for (int nf = 0; nf < 4; ++nf) {
      const int col = n0 + wn + nf * 16 + l15;
      const float bv = bias[col];
#pragma unroll
      for (int mf = 0; mf < MF; ++mf) {
#pragma unroll
        for (int r = 0; r < 4; ++r) {
          const int row = m0 + wm + mf * 16 + quad * 4 + r;
          const float v = (acc[mf][nf][r] + bv) * scale;
          if (mode == 0) ((u16*)args.out[z])[(size_t)row * D_MODEL + col] = f2bf(v);
          else           ((float*)args.out[z])[(size_t)row * D_MODEL + col] = v;
        }
      }
    }
  }
}

// ---------------------------------------------------------------- flash attention (S^T / O^T form, LDS-free inner loop)
// Q pre-scaled by (1/8)*log2(e): exp2-domain softmax, no max subtraction (scores |~3|).
// Block: 64 q, 4 waves = key-quarters; each wave owns both q-subtiles and keys
// [w*1024,+1024) in 32 subtiles. K/V frags lane-linear in Kpk/Vpk -> direct
// global->VGPR loads, 2-phase register double buffer. LDS only for the epilogue,
// done in TWO phases (one per q-subtile) so LDS = 34KB -> 3 blocks/CU resident
// (grid 768 = exactly 3x256, zero dispatch tail; round-6 fix: was 67.5KB/2 blocks).
// S^T = K.Q^T via mfma_32x32x16 (C: col=q=lane&31, row=key=(r&3)+8*(r>>2)+4*(lane>>5));
// PV B-frag(u) = p[8u..8u+7] packed in-register; kappa key-order baked into Vpk.
__global__ __launch_bounds__(256, 3) void flash_kernel(
    const u16* __restrict__ Qb, const u16* __restrict__ Kpk,
    const u16* __restrict__ Vpk, const int* __restrict__ mask,
    u16* __restrict__ Ctx) {
  __shared__ char smem[34816];  // 32KB O-partials (per phase) + 2KB l-partials

  const int tid = threadIdx.x;
  const int w = tid >> 6, l = tid & 63;   // w = key-quarter
  const int l31 = l & 31, g = l >> 5;
  const int h = blockIdx.y;
  const int q0 = blockIdx.x * 64;

  // Q B-frags (B[k=d][n=q]: n=lane&31, k=(lane>>5)*8+j) for both q-subtiles
  bf16x8 qf[2][4];
#pragma unroll
  for (int qs = 0; qs < 2; ++qs) {
    const u16* qrow = Qb + (size_t)(q0 + qs * 32 + l31) * D_MODEL + h * D_HEAD + g * 8;
#pragma unroll
    for (int s = 0; s < 4; ++s) qf[qs][s] = *(const bf16x8*)(qrow + s * 16);
  }

  // this wave's key range: subtiles st = w*32 + it, it in [0,32)
  const u16* kb = Kpk + ((size_t)h * 128 + w * 32) * 2048 + l * 8;
  const u16* vb = Vpk + ((size_t)h * 128 + w * 32) * 2048 + l * 8;
  const int* mk = mask + w * 1024 + l31;

  f32x16 oacc[2][2] = {};  // [qs][d-half]
  float lsum[2] = {0.f, 0.f};

  bf16x8 kfA[4], vfA[4], kfB[4], vfB[4];
  int mvA, mvB;

  // load tile 0 into A regs
  mvA = mk[0];
#pragma unroll
  for (int c = 0; c < 4; ++c) kfA[c] = *(const bf16x8*)(kb + c * 512);
#pragma unroll
  for (int c = 0; c < 4; ++c) vfA[c] = *(const bf16x8*)(vb + c * 512);

#define FLASH_COMPUTE(KF, VF, MV)                                              \
  {                                                                            \
    const unsigned long long mb = __ballot((MV) != 0);                         \
    _Pragma("unroll") for (int qs = 0; qs < 2; ++qs) {                         \
      f32x16 sacc = {};                                                        \
      _Pragma("unroll") for (int s = 0; s < 4; ++s)                            \
          sacc = __builtin_amdgcn_mfma_f32_32x32x16_bf16(KF[s], qf[qs][s],     \
                                                         sacc, 0, 0, 0);       \
      _Pragma("unroll") for (int r = 0; r < 16; ++r)                           \
          sacc[r] = __builtin_amdgcn_exp2f(sacc[r]);                           \
      if (mb + 1ull != 0ull) {                                                 \
        const unsigned mh = (unsigned)(mb >> (4 * g));                         \
        _Pragma("unroll") for (int r = 0; r < 16; ++r)                         \
            if (!((mh >> ((r & 3) + 8 * (r >> 2))) & 1u)) sacc[r] = 0.f;       \
      }                                                                        \
      float ts = 0.f;                                                          \
      _Pragma("unroll") for (int r = 0; r < 16; ++r) ts += sacc[r];            \
      lsum[qs] += ts;                                                          \
      u32 pk[8];                                                               \
      _Pragma("unroll") for (int i = 0; i < 8; ++i)                            \
          pk[i] = pk2bf(sacc[2 * i], sacc[2 * i + 1]);                         \
      _Pragma("unroll") for (int u = 0; u < 2; ++u) {                          \
        union { u32 u4[4]; bf16x8 s; } bp;                                     \
        _Pragma("unroll") for (int i = 0; i < 4; ++i) bp.u4[i] = pk[4 * u + i];\
        oacc[qs][0] = __builtin_amdgcn_mfma_f32_32x32x16_bf16(VF[u], bp.s,     \
                                                              oacc[qs][0], 0, 0, 0); \
        oacc[qs][1] = __builtin_amdgcn_mfma_f32_32x32x16_bf16(VF[2 + u], bp.s, \
                                                              oacc[qs][1], 0, 0, 0); \
      }                                                                        \
    }                                                                          \
  }

  for (int p = 0; p < 16; ++p) {
    {  // phase 0: prefetch tile 2p+1 into B, compute tile 2p from A
      const int nt = 2 * p + 1;
      mvB = mk[nt * 32];
      const u16* kn = kb + (size_t)nt * 2048;
      const u16* vn = vb + (size_t)nt * 2048;
#pragma unroll
      for (int c = 0; c < 4; ++c) kfB[c] = *(const bf16x8*)(kn + c * 512);
#pragma unroll
      for (int c = 0; c < 4; ++c) vfB[c] = *(const bf16x8*)(vn + c * 512);
      FLASH_COMPUTE(kfA, vfA, mvA)
    }
    {  // phase 1: prefetch tile 2p+2 (clamped) into A, compute tile 2p+1 from B
      const int nt = (2 * p + 2 < 32) ? 2 * p + 2 : 31;
      mvA = mk[nt * 32];
      const u16* kn = kb + (size_t)nt * 2048;
      const u16* vn = vb + (size_t)nt * 2048;
#pragma unroll
      for (int c = 0; c < 4; ++c) kfA[c] = *(const bf16x8*)(kn + c * 512);
#pragma unroll
      for (int c = 0; c < 4; ++c) vfA[c] = *(const bf16x8*)(vn + c * 512);
      FLASH_COMPUTE(kfB, vfB, mvB)
    }
  }
#undef FLASH_COMPUTE

  // ---- combine 4 key-quarter partials, two phases (one per q-subtile)
  float* Ol = (float*)smem;             // [(kq*2+db)*16 + r]*64 + l  (32KB)
  float* Ll = (float*)(smem + 32768);   // [kq*128 + qs*64 + l]       (2KB)
  Ll[w * 128 + l] = lsum[0];
  Ll[w * 128 + 64 + l] = lsum[1];
#pragma unroll
  for (int ph = 0; ph < 2; ++ph) {
    __syncthreads();
#pragma unroll
    for (int db = 0; db < 2; ++db)
#pragma unroll
      for (int r = 0; r < 16; ++r)
        Ol[((w * 2 + db) * 16 + r) * 64 + l] = oacc[ph][db][r];
    __syncthreads();

    float Lt = 0.f;
#pragma unroll
    for (int kq = 0; kq < 4; ++kq)
      Lt += Ll[kq * 128 + ph * 64 + l] + Ll[kq * 128 + ph * 64 + (l ^ 32)];
    const float linv = 1.0f / Lt;

    // wave w outputs d-half db=w&1, r-quarters rr=(w>>1)*2+t
    const int db = w & 1;
#pragma unroll
    for (int t = 0; t < 2; ++t) {
      const int rr = (w >> 1) * 2 + t;
      float v[4];
#pragma unroll
      for (int i = 0; i < 4; ++i) {
        const int r = rr * 4 + i;
        float acc = 0.f;
#pragma unroll
        for (int kq = 0; kq < 4; ++kq)
          acc += Ol[((kq * 2 + db) * 16 + r) * 64 + l];
        v[i] = acc * linv;
      }
      // d = i + 8*rr + 4g + 32*db (from C-layout row formula)
      u16* cp = Ctx + (size_t)(q0 + ph * 32 + l31) * D_MODEL + h * D_HEAD + db * 32 + rr * 8 + 4 * g;
      *(u32*)(cp) = pk2bf(v[0], v[1]);
      *(u32*)(cp + 2) = pk2bf(v[2], v[3]);
    }
  }
}

// ---------------------------------------------------------------- launch
extern "C" void kernel_launch(void* const* d_in, const int* in_sizes, int n_in,
                              void* d_out, int out_size, void* d_ws, size_t ws_size,
                              hipStream_t stream) {
  const float* query = (const float*)d_in[0];
  const float* key   = (const float*)d_in[1];
  const float* value = (const float*)d_in[2];
  const int*   maskp = (const int*)d_in[3];
  const float* Wq = (const float*)d_in[4];
  const float* bq = (const float*)d_in[5];
  const float* Wk = (const float*)d_in[6];
  const float* bk = (const float*)d_in[7];
  const float* Wv = (const float*)d_in[8];
  const float* bv = (const float*)d_in[9];
  const float* Wo = (const float*)d_in[10];
  const float* bo = (const float*)d_in[11];

  char* ws = (char*)d_ws;
  const size_t SZX = (size_t)S_LEN * D_MODEL * 2;   // 6.29 MB
  const size_t SZW = (size_t)D_MODEL * D_MODEL * 2; // 1.18 MB
  u16* Xq  = (u16*)(ws);
  u16* Xk  = (u16*)(ws + SZX);
  u16* Xv  = (u16*)(ws + 2 * SZX);
  u16* Qb  = (u16*)(ws + 3 * SZX);
  u16* Kpk = (u16*)(ws + 4 * SZX);
  u16* Vpk = (u16*)(ws + 5 * SZX);
  u16* Wqb = (u16*)(ws + 6 * SZX);
  u16* Wkb = (u16*)(ws + 6 * SZX + SZW);
  u16* Wvb = (u16*)(ws + 6 * SZX + 2 * SZW);
  u16* Wob = (u16*)(ws + 6 * SZX + 3 * SZW);
  u16* Ctx = Xq;  // Xq dead after QKV projection

  // one fused conversion launch: z=0..2 activations, z=3..6 weights
  CvtArgs7 cc;
  cc.s[0] = query; cc.s[1] = key; cc.s[2] = value;
  cc.s[3] = Wq; cc.s[4] = Wk; cc.s[5] = Wv; cc.s[6] = Wo;
  cc.d[0] = Xq; cc.d[1] = Xk; cc.d[2] = Xv;
  cc.d[3] = Wqb; cc.d[4] = Wkb; cc.d[5] = Wvb; cc.d[6] = Wob;
  const long nact = (long)S_LEN * D_MODEL, nw = (long)D_MODEL * D_MODEL;
  cc.n[0] = cc.n[1] = cc.n[2] = nact;
  cc.n[3] = cc.n[4] = cc.n[5] = cc.n[6] = nw;
  cvt8_kernel<<<dim3(1536, 1, 7), 256, 0, stream>>>(cc);

  // QKV projections; Q folds 1/sqrt(Dh)*log2(e); K/V stored in flash frag-order
  ProjArgs pa;
  pa.A[0] = Xq;  pa.A[1] = Xk;  pa.A[2] = Xv;
  pa.W[0] = Wqb; pa.W[1] = Wkb; pa.W[2] = Wvb;
  pa.bias[0] = bq; pa.bias[1] = bk; pa.bias[2] = bv;
  pa.out[0] = Qb; pa.out[1] = Kpk; pa.out[2] = Vpk;
  pa.scale[0] = 0.125f * 1.4426950408889634f; pa.scale[1] = 1.f; pa.scale[2] = 1.f;
  pa.mode[0] = 0; pa.mode[1] = 3; pa.mode[2] = 4;
  proj_kernel<128><<<dim3(32, 6, 3), 256, 0, stream>>>(pa);

  // flash attention -> Ctx (bf16, S x D); 64 q per block, 768 blocks = 3/CU
  flash_kernel<<<dim3(64, N_HEADS, 1), 256, 0, stream>>>(Qb, Kpk, Vpk, maskp, Ctx);

  // output projection -> fp32 d_out (TM=64 -> 384 blocks)
  ProjArgs po;
  po.A[0] = Ctx; po.A[1] = Ctx; po.A[2] = Ctx;
  po.W[0] = Wob; po.W[1] = Wob; po.W[2] = Wob;
  po.bias[0] = bo; po.bias[1] = bo; po.bias[2] = bo;
  po.out[0] = d_out; po.out[1] = d_out; po.out[2] = d_out;
  po.scale[0] = 1.f; po.scale[1] = 1.f; po.scale[2] = 1.f;
  po.mode[0] = 2; po.mode[1] = 2; po.mode[2] = 2;
  proj_kernel<64><<<dim3(64, 6, 1), 256, 0, stream>>>(po);
}

// Round 8
// 210.370 us; speedup vs baseline: 1.6641x; 1.6641x over previous
//
#include <hip/hip_runtime.h>

// Problem constants: B=1, S=4096, D=768, H=12, Dh=64
#define S_LEN 4096
#define D_MODEL 768
#define N_HEADS 12
#define D_HEAD 64

typedef short bf16x8 __attribute__((ext_vector_type(8)));   // MFMA A/B operand (8 bf16, 4 VGPRs)
typedef float f32x4 __attribute__((ext_vector_type(4)));    // MFMA C/D operand (16x16)
typedef float f32x16 __attribute__((ext_vector_type(16)));  // MFMA C/D operand (32x32)
typedef float f32x4v __attribute__((ext_vector_type(4)));
typedef unsigned short u16;
typedef unsigned short u16x8 __attribute__((ext_vector_type(8)));
typedef unsigned int u32;

// fp32 -> bf16 round-to-nearest-even
__device__ __forceinline__ u16 f2bf(float f) {
  unsigned u = __float_as_uint(f);
  u += 0x7FFFu + ((u >> 16) & 1u);
  return (u16)(u >> 16);
}

// pack two fp32 -> 2x bf16 in one u32 (round-half-up)
__device__ __forceinline__ u32 pk2bf(float lo, float hi) {
  u32 a = __float_as_uint(hi) + 0x8000u;
  u32 b = __float_as_uint(lo) + 0x8000u;
  return __builtin_amdgcn_perm(a, b, 0x07060302u);
}

// async global->LDS, 16B per lane; LDS dest is wave-uniform base + lane*16 (m104 caveat)
__device__ __forceinline__ void gl_lds16(const void* g, void* l) {
  __builtin_amdgcn_global_load_lds(
      (const __attribute__((address_space(1))) void*)g,
      (__attribute__((address_space(3))) void*)l, 16, 0, 0);
}

// ---------------------------------------------------------------- conversion (single fused launch)
struct CvtArgs7 {
  const float* s[7];
  u16* d[7];
  long n[7];
};

__global__ __launch_bounds__(256) void cvt8_kernel(CvtArgs7 a) {
  const int z = blockIdx.z;
  const float* s = a.s[z];
  u16* d = a.d[z];
  long i = ((long)blockIdx.x * 256 + threadIdx.x) * 8;
  if (i >= a.n[z]) return;
  f32x4v v0 = *(const f32x4v*)(s + i);
  f32x4v v1 = *(const f32x4v*)(s + i + 4);
  u16x8 o;
#pragma unroll
  for (int j = 0; j < 4; ++j) { o[j] = f2bf(v0[j]); o[j + 4] = f2bf(v1[j]); }
  *(u16x8*)(d + i) = o;
}

// ---------------------------------------------------------------- projection GEMM
// Out[m][n] = (sum_k A[m][k] * W[n][k] + bias[n]) * scale
// TM = M-tile (128 or 64); N-tile fixed 128.
// mode 0: bf16 row-major (ld 768)
// mode 2: fp32 row-major
// mode 3: packed-K frag order: Kpk[((h*128+st)*4+s)*512 + (g*32+l31)*8 + j]
//         = K[seq=st*32+l31][d=s*16+g*8+j]  (flash S^T A-operand sequence)
// mode 4: packed-V frag order: Vpk[((h*128+st)*4+db*2+u)*512 + (g*32+l31)*8 + j]
//         = V[key=st*32+16u+(j&3)+8*(j>>2)+4g][d=db*32+l31]  (flash PV A-operand,
//         kappa swap-bits-2/3 baked in to match P's B-frag key order)
// Modes 3/4 (TM=128 only) bounce through 32KB LDS so global stores are
// coalesced dwordx4 (round-6 lesson: scattered u16 stores are the proj cost).
struct ProjArgs {
  const u16* A[3];
  const u16* W[3];
  const float* bias[3];
  void* out[3];
  float scale[3];
  int mode[3];
};

template <int TM>
__global__ __launch_bounds__(256, 2) void proj_kernel(ProjArgs args) {
  constexpr int MF = TM / 32;       // m-frags per wave
  constexpr int CA = TM / 16;       // A staging chunks (1KB each)
  const int z = blockIdx.z;
  const u16* __restrict__ A = args.A[z];
  const u16* __restrict__ W = args.W[z];
  const float* __restrict__ bias = args.bias[z];
  const float scale = args.scale[z];
  const int mode = args.mode[z];

  __shared__ u16 Al[TM * 32];
  __shared__ u16 Bl[128 * 32];
  __shared__ u16 Ep[TM == 128 ? 16384 : 1];  // packed-epilogue bounce (32KB)

  const int tid = threadIdx.x;
  const int w = tid >> 6, l = tid & 63;
  const int l15 = l & 15, quad = l >> 4;
  const int m0 = blockIdx.x * TM;
  const int n0 = blockIdx.y * 128;
  const int wm = (w & 1) * (TM / 2), wn = (w >> 1) * 64;
  const int crow = l >> 2, ccol = (l & 3) * 8;

  f32x4 acc[MF][4] = {};

  for (int kt = 0; kt < 24; ++kt) {
    const int k0 = kt * 32;
#pragma unroll
    for (int i = 0; i < CA / 4; ++i) {
      const int sub = w * (CA / 4) + i;
      const int row = sub * 16 + crow;
      gl_lds16(&A[(size_t)(m0 + row) * D_MODEL + k0 + ccol], &Al[sub * 512 + l * 8]);
    }
#pragma unroll
    for (int i = 0; i < 2; ++i) {
      const int sub = w * 2 + i;
      const int row = sub * 16 + crow;
      gl_lds16(&W[(size_t)(n0 + row) * D_MODEL + k0 + ccol], &Bl[sub * 512 + l * 8]);
    }
    __syncthreads();
    bf16x8 af[MF], bfr[4];
#pragma unroll
    for (int mf = 0; mf < MF; ++mf)
      af[mf] = *(const bf16x8*)&Al[(wm + mf * 16 + l15) * 32 + quad * 8];
#pragma unroll
    for (int nf = 0; nf < 4; ++nf)
      bfr[nf] = *(const bf16x8*)&Bl[(wn + nf * 16 + l15) * 32 + quad * 8];
#pragma unroll
    for (int mf = 0; mf < MF; ++mf)
#pragma unroll
      for (int nf = 0; nf < 4; ++nf)
        acc[mf][nf] = __builtin_amdgcn_mfma_f32_16x16x32_bf16(af[mf], bfr[nf], acc[mf][nf], 0, 0, 0);
    __syncthreads();
  }

  // C/D layout: col = lane&15, row = quad*4 + reg (m89/m91 verified)
  if (mode == 3 || mode == 4) {
    // write packed layout into Ep, then coalesced copy-out
#pragma unroll
    for (int nf = 0; nf < 4; ++nf) {
      const float bv = bias[n0 + wn + nf * 16 + l15];
#pragma unroll
      for (int mf = 0; mf < MF; ++mf) {
#pragma unroll
        for (int r = 0; r < 4; ++r) {
          const float v = acc[mf][nf][r] + bv;
          int off;
          if (mode == 3) {
            // chunk = hloc*16 + sloc*4 + s ; hloc=w>>1, sloc=(w&1)*2+(mf>>1), s=nf
            // intra = ((l15>>3)*32 + (mf&1)*16 + quad*4 + r)*8 + (l15&7)
            off = (((w >> 1) * 16 + ((w & 1) * 2 + (mf >> 1)) * 4 + nf) << 9) +
                  (((l15 >> 3) * 32 + (mf & 1) * 16 + quad * 4 + r) << 3) + (l15 & 7);
          } else {
            // chunk = hloc*16 + sloc*4 + db*2 + u ; db=nf>>1, u=mf&1
            // intra = ((quad&1)*32 + (nf&1)*16 + l15)*8 + r + 4*(quad>>1)
            off = (((w >> 1) * 16 + ((w & 1) * 2 + (mf >> 1)) * 4 + (nf >> 1) * 2 + (mf & 1)) << 9) +
                  (((quad & 1) * 32 + (nf & 1) * 16 + l15) << 3) + r + 4 * (quad >> 1);
          }
          Ep[off] = f2bf(v);
        }
      }
    }
    __syncthreads();
    // copy-out: per hloc, 16 contiguous 1KB chunks at ((hh0+hloc)*128+st0)*4
    const int hh0 = n0 >> 6, st0 = m0 >> 5;
    u16* outp = (u16*)args.out[z];
#pragma unroll
    for (int hloc = 0; hloc < 2; ++hloc) {
      u16* dst = outp + ((size_t)((hh0 + hloc) * 128 + st0) * 4) * 512;
#pragma unroll
      for (int c = 0; c < 4; ++c) {
        u16x8 v = *(u16x8*)&Ep[hloc * 8192 + w * 2048 + c * 512 + l * 8];
        *(u16x8*)(dst + w * 2048 + c * 512 + l * 8) = v;
      }
    }
  } else {
#pragma unroll
    for (int nf = 0; nf < 4; ++nf) {
      const int col = n0 + wn + nf * 16 + l15;
      const float bv = bias[col];
#pragma unroll
      for (int mf = 0; mf < MF; ++mf) {
#pragma unroll
        for (int r = 0; r < 4; ++r) {
          const int row = m0 + wm + mf * 16 + quad * 4 + r;
          const float v = (acc[mf][nf][r] + bv) * scale;
          if (mode == 0) ((u16*)args.out[z])[(size_t)row * D_MODEL + col] = f2bf(v);
          else           ((float*)args.out[z])[(size_t)row * D_MODEL + col] = v;
        }
      }
    }
  }
}

// ---------------------------------------------------------------- flash attention (S^T / O^T form, LDS-free inner loop)
// Q pre-scaled by (1/8)*log2(e): exp2-domain softmax, no max subtraction (scores |~3|).
// Block: 64 q, 4 waves = key-quarters; each wave owns both q-subtiles and keys
// [w*1024,+1024) in 32 subtiles. K/V frags lane-linear in Kpk/Vpk -> direct
// global->VGPR loads, 2-phase register double buffer. LDS only for the epilogue,
// two phases (one per q-subtile) -> 34KB. __launch_bounds__(256,2): round-7 lesson —
// requesting 3 waves/EU capped VGPRs at 84, spilled oacc to scratch (+750MB HBM,
// 3x slower). With ~120 VGPRs the HW can still co-resident 4 blocks/CU (LDS 136KB).
// S^T = K.Q^T via mfma_32x32x16 (C: col=q=lane&31, row=key=(r&3)+8*(r>>2)+4*(lane>>5));
// PV B-frag(u) = p[8u..8u+7] packed in-register; kappa key-order baked into Vpk.
__global__ __launch_bounds__(256, 2) void flash_kernel(
    const u16* __restrict__ Qb, const u16* __restrict__ Kpk,
    const u16* __restrict__ Vpk, const int* __restrict__ mask,
    u16* __restrict__ Ctx) {
  __shared__ char smem[34816];  // 32KB O-partials (per phase) + 2KB l-partials

  const int tid = threadIdx.x;
  const int w = tid >> 6, l = tid & 63;   // w = key-quarter
  const int l31 = l & 31, g = l >> 5;
  const int h = blockIdx.y;
  const int q0 = blockIdx.x * 64;

  // Q B-frags (B[k=d][n=q]: n=lane&31, k=(lane>>5)*8+j) for both q-subtiles
  bf16x8 qf[2][4];
#pragma unroll
  for (int qs = 0; qs < 2; ++qs) {
    const u16* qrow = Qb + (size_t)(q0 + qs * 32 + l31) * D_MODEL + h * D_HEAD + g * 8;
#pragma unroll
    for (int s = 0; s < 4; ++s) qf[qs][s] = *(const bf16x8*)(qrow + s * 16);
  }

  // this wave's key range: subtiles st = w*32 + it, it in [0,32)
  const u16* kb = Kpk + ((size_t)h * 128 + w * 32) * 2048 + l * 8;
  const u16* vb = Vpk + ((size_t)h * 128 + w * 32) * 2048 + l * 8;
  const int* mk = mask + w * 1024 + l31;

  f32x16 oacc[2][2] = {};  // [qs][d-half]
  float lsum[2] = {0.f, 0.f};

  bf16x8 kfA[4], vfA[4], kfB[4], vfB[4];
  int mvA, mvB;

  // load tile 0 into A regs
  mvA = mk[0];
#pragma unroll
  for (int c = 0; c < 4; ++c) kfA[c] = *(const bf16x8*)(kb + c * 512);
#pragma unroll
  for (int c = 0; c < 4; ++c) vfA[c] = *(const bf16x8*)(vb + c * 512);

#define FLASH_COMPUTE(KF, VF, MV)                                              \
  {                                                                            \
    const unsigned long long mb = __ballot((MV) != 0);                         \
    _Pragma("unroll") for (int qs = 0; qs < 2; ++qs) {                         \
      f32x16 sacc = {};                                                        \
      _Pragma("unroll") for (int s = 0; s < 4; ++s)                            \
          sacc = __builtin_amdgcn_mfma_f32_32x32x16_bf16(KF[s], qf[qs][s],     \
                                                         sacc, 0, 0, 0);       \
      _Pragma("unroll") for (int r = 0; r < 16; ++r)                           \
          sacc[r] = __builtin_amdgcn_exp2f(sacc[r]);                           \
      if (mb + 1ull != 0ull) {                                                 \
        const unsigned mh = (unsigned)(mb >> (4 * g));                         \
        _Pragma("unroll") for (int r = 0; r < 16; ++r)                         \
            if (!((mh >> ((r & 3) + 8 * (r >> 2))) & 1u)) sacc[r] = 0.f;       \
      }                                                                        \
      float ts = 0.f;                                                          \
      _Pragma("unroll") for (int r = 0; r < 16; ++r) ts += sacc[r];            \
      lsum[qs] += ts;                                                          \
      u32 pk[8];                                                               \
      _Pragma("unroll") for (int i = 0; i < 8; ++i)                            \
          pk[i] = pk2bf(sacc[2 * i], sacc[2 * i + 1]);                         \
      _Pragma("unroll") for (int u = 0; u < 2; ++u) {                          \
        union { u32 u4[4]; bf16x8 s; } bp;                                     \
        _Pragma("unroll") for (int i = 0; i < 4; ++i) bp.u4[i] = pk[4 * u + i];\
        oacc[qs][0] = __builtin_amdgcn_mfma_f32_32x32x16_bf16(VF[u], bp.s,     \
                                                              oacc[qs][0], 0, 0, 0); \
        oacc[qs][1] = __builtin_amdgcn_mfma_f32_32x32x16_bf16(VF[2 + u], bp.s, \
                                                              oacc[qs][1], 0, 0, 0); \
      }                                                                        \
    }                                                                          \
  }

  for (int p = 0; p < 16; ++p) {
    {  // phase 0: prefetch tile 2p+1 into B, compute tile 2p from A
      const int nt = 2 * p + 1;
      mvB = mk[nt * 32];
      const u16* kn = kb + (size_t)nt * 2048;
      const u16* vn = vb + (size_t)nt * 2048;
#pragma unroll
      for (int c = 0; c < 4; ++c) kfB[c] = *(const bf16x8*)(kn + c * 512);
#pragma unroll
      for (int c = 0; c < 4; ++c) vfB[c] = *(const bf16x8*)(vn + c * 512);
      FLASH_COMPUTE(kfA, vfA, mvA)
    }
    {  // phase 1: prefetch tile 2p+2 (clamped) into A, compute tile 2p+1 from B
      const int nt = (2 * p + 2 < 32) ? 2 * p + 2 : 31;
      mvA = mk[nt * 32];
      const u16* kn = kb + (size_t)nt * 2048;
      const u16* vn = vb + (size_t)nt * 2048;
#pragma unroll
      for (int c = 0; c < 4; ++c) kfA[c] = *(const bf16x8*)(kn + c * 512);
#pragma unroll
      for (int c = 0; c < 4; ++c) vfA[c] = *(const bf16x8*)(vn + c * 512);
      FLASH_COMPUTE(kfB, vfB, mvB)
    }
  }
#undef FLASH_COMPUTE

  // ---- combine 4 key-quarter partials, two phases (one per q-subtile)
  float* Ol = (float*)smem;             // [(kq*2+db)*16 + r]*64 + l  (32KB)
  float* Ll = (float*)(smem + 32768);   // [kq*128 + qs*64 + l]       (2KB)
  Ll[w * 128 + l] = lsum[0];
  Ll[w * 128 + 64 + l] = lsum[1];
#pragma unroll
  for (int ph = 0; ph < 2; ++ph) {
    __syncthreads();
#pragma unroll
    for (int db = 0; db < 2; ++db)
#pragma unroll
      for (int r = 0; r < 16; ++r)
        Ol[((w * 2 + db) * 16 + r) * 64 + l] = oacc[ph][db][r];
    __syncthreads();

    float Lt = 0.f;
#pragma unroll
    for (int kq = 0; kq < 4; ++kq)
      Lt += Ll[kq * 128 + ph * 64 + l] + Ll[kq * 128 + ph * 64 + (l ^ 32)];
    const float linv = 1.0f / Lt;

    // wave w outputs d-half db=w&1, r-quarters rr=(w>>1)*2+t
    const int db = w & 1;
#pragma unroll
    for (int t = 0; t < 2; ++t) {
      const int rr = (w >> 1) * 2 + t;
      float v[4];
#pragma unroll
      for (int i = 0; i < 4; ++i) {
        const int r = rr * 4 + i;
        float acc = 0.f;
#pragma unroll
        for (int kq = 0; kq < 4; ++kq)
          acc += Ol[((kq * 2 + db) * 16 + r) * 64 + l];
        v[i] = acc * linv;
      }
      // d = i + 8*rr + 4g + 32*db (from C-layout row formula)
      u16* cp = Ctx + (size_t)(q0 + ph * 32 + l31) * D_MODEL + h * D_HEAD + db * 32 + rr * 8 + 4 * g;
      *(u32*)(cp) = pk2bf(v[0], v[1]);
      *(u32*)(cp + 2) = pk2bf(v[2], v[3]);
    }
  }
}

// ---------------------------------------------------------------- launch
extern "C" void kernel_launch(void* const* d_in, const int* in_sizes, int n_in,
                              void* d_out, int out_size, void* d_ws, size_t ws_size,
                              hipStream_t stream) {
  const float* query = (const float*)d_in[0];
  const float* key   = (const float*)d_in[1];
  const float* value = (const float*)d_in[2];
  const int*   maskp = (const int*)d_in[3];
  const float* Wq = (const float*)d_in[4];
  const float* bq = (const float*)d_in[5];
  const float* Wk = (const float*)d_in[6];
  const float* bk = (const float*)d_in[7];
  const float* Wv = (const float*)d_in[8];
  const float* bv = (const float*)d_in[9];
  const float* Wo = (const float*)d_in[10];
  const float* bo = (const float*)d_in[11];

  char* ws = (char*)d_ws;
  const size_t SZX = (size_t)S_LEN * D_MODEL * 2;   // 6.29 MB
  const size_t SZW = (size_t)D_MODEL * D_MODEL * 2; // 1.18 MB
  u16* Xq  = (u16*)(ws);
  u16* Xk  = (u16*)(ws + SZX);
  u16* Xv  = (u16*)(ws + 2 * SZX);
  u16* Qb  = (u16*)(ws + 3 * SZX);
  u16* Kpk = (u16*)(ws + 4 * SZX);
  u16* Vpk = (u16*)(ws + 5 * SZX);
  u16* Wqb = (u16*)(ws + 6 * SZX);
  u16* Wkb = (u16*)(ws + 6 * SZX + SZW);
  u16* Wvb = (u16*)(ws + 6 * SZX + 2 * SZW);
  u16* Wob = (u16*)(ws + 6 * SZX + 3 * SZW);
  u16* Ctx = Xq;  // Xq dead after QKV projection

  // one fused conversion launch: z=0..2 activations, z=3..6 weights
  CvtArgs7 cc;
  cc.s[0] = query; cc.s[1] = key; cc.s[2] = value;
  cc.s[3] = Wq; cc.s[4] = Wk; cc.s[5] = Wv; cc.s[6] = Wo;
  cc.d[0] = Xq; cc.d[1] = Xk; cc.d[2] = Xv;
  cc.d[3] = Wqb; cc.d[4] = Wkb; cc.d[5] = Wvb; cc.d[6] = Wob;
  const long nact = (long)S_LEN * D_MODEL, nw = (long)D_MODEL * D_MODEL;
  cc.n[0] = cc.n[1] = cc.n[2] = nact;
  cc.n[3] = cc.n[4] = cc.n[5] = cc.n[6] = nw;
  cvt8_kernel<<<dim3(1536, 1, 7), 256, 0, stream>>>(cc);

  // QKV projections; Q folds 1/sqrt(Dh)*log2(e); K/V stored in flash frag-order
  ProjArgs pa;
  pa.A[0] = Xq;  pa.A[1] = Xk;  pa.A[2] = Xv;
  pa.W[0] = Wqb; pa.W[1] = Wkb; pa.W[2] = Wvb;
  pa.bias[0] = bq; pa.bias[1] = bk; pa.bias[2] = bv;
  pa.out[0] = Qb; pa.out[1] = Kpk; pa.out[2] = Vpk;
  pa.scale[0] = 0.125f * 1.4426950408889634f; pa.scale[1] = 1.f; pa.scale[2] = 1.f;
  pa.mode[0] = 0; pa.mode[1] = 3; pa.mode[2] = 4;
  proj_kernel<128><<<dim3(32, 6, 3), 256, 0, stream>>>(pa);

  // flash attention -> Ctx (bf16, S x D); 64 q per block, 768 blocks
  flash_kernel<<<dim3(64, N_HEADS, 1), 256, 0, stream>>>(Qb, Kpk, Vpk, maskp, Ctx);

  // output projection -> fp32 d_out (TM=64 -> 384 blocks)
  ProjArgs po;
  po.A[0] = Ctx; po.A[1] = Ctx; po.A[2] = Ctx;
  po.W[0] = Wob; po.W[1] = Wob; po.W[2] = Wob;
  po.bias[0] = bo; po.bias[1] = bo; po.bias[2] = bo;
  po.out[0] = d_out; po.out[1] = d_out; po.out[2] = d_out;
  po.scale[0] = 1.f; po.scale[1] = 1.f; po.scale[2] = 1.f;
  po.mode[0] = 2; po.mode[1] = 2; po.mode[2] = 2;
  proj_kernel<64><<<dim3(64, 6, 1), 256, 0, stream>>>(po);
}